// Round 17
// baseline (243.646 us; speedup 1.0000x reference)
//
#include <hip/hip_runtime.h>
#include <hip/hip_bf16.h>
#include <cstdint>
#include <cstring>

#define ND 48
#define LQ 2304      // 48*48
#define CCH 96
#define HWD 96
#define CHW (CCH*HWD*HWD)   // 884736
#define HW2 (HWD*HWD)       // 9216
#define K2P 2560     // padded K (50-grid: 2500 live, cols>=2500 zero)
#define NJ2 384      // 96 ch * 4 (s,t)
#define KSP 384      // split-GEMM K (288 live = 3 parts x 96, padded to 3x128)

typedef __attribute__((ext_vector_type(8))) short bf16x8;
typedef __attribute__((ext_vector_type(4))) float f32x4;

__device__ __forceinline__ float4 ld4u(const float* p) {  // 4B-aligned float4 load
  float4 v; __builtin_memcpy(&v, p, 16); return v;
}

// ---------------- K0a: downsample fg/bg to (c,p) layout (fully parallel copy)
__global__ void k_downc(const float* __restrict__ fg, const float* __restrict__ bg,
                        float* __restrict__ fgdT, float* __restrict__ bgdT, size_t sd) {
  int b = blockIdx.z;
  int id = blockIdx.x * 256 + threadIdx.x;   // < CCH*LQ = 221184 (864 blocks)
  int c = id / LQ, p = id % LQ;
  int py = p / ND, px = p % ND;
  size_t src = (size_t)b * CHW + (size_t)c * HW2 + (size_t)(2 * py) * HWD + 2 * px;
  fgdT[(size_t)b * sd + id] = fg[src];       // id == c*LQ + p (same layout)
  bgdT[(size_t)b * sd + id] = bg[src];
}

// ---------------- K0a': per-pos squared norm of bgd (reads L2-warm bgdT)
__global__ void k_n2(const float* __restrict__ bgdT, float* __restrict__ n2,
                     size_t sd, size_t sp) {
  int b = blockIdx.z;
  const float* bT = bgdT + (size_t)b * sd;
  int p = blockIdx.x * 256 + threadIdx.x;
  if (p >= LQ) return;
  float s = 0.f;
  for (int c = 0; c < CCH; ++c) {            // same c-ascending sum order as before
    float g = bT[c * LQ + p];
    s += g * g;
  }
  n2[(size_t)b * sp + p] = s;
}

// ---------------- K0b: patch norms (rnorm) and mask means (mval)
__global__ void k_aux(const float* __restrict__ n2, const float* __restrict__ mask,
                      float* __restrict__ rnorm, float* __restrict__ mval, size_t sp) {
  int b = blockIdx.z;
  const float* n2b = n2 + (size_t)b * sp;
  const float* mb = mask + (size_t)b * HW2;
  float* rn = rnorm + (size_t)b * sp;
  float* mv = mval + (size_t)b * sp;
  int p = blockIdx.x * 256 + threadIdx.x;
  if (p >= LQ) return;
  int py = p / ND, px = p % ND;
  float ssq = 0.f, ms = 0.f;
  for (int dy = -1; dy <= 1; ++dy)
    for (int dx = -1; dx <= 1; ++dx) {
      int yy = py + dy, xx = px + dx;
      if (yy >= 0 && yy < ND && xx >= 0 && xx < ND) {
        ssq += n2b[yy * ND + xx];
        ms  += mb[(2 * yy) * HWD + 2 * xx];
      }
    }
  rn[p] = 1.0f / sqrtf(ssq + 864.0f * 1e-9f);
  mv[p] = ms * (1.0f / 9.0f);
}

// ---------------- K1a: build split operands for MFMA rgemm
__global__ __launch_bounds__(256) void k_split(const float* __restrict__ fgdT,
                                               const float* __restrict__ bgdT,
                                               __hip_bfloat16* __restrict__ AB,
                                               size_t sd, size_t sAB) {
  int b = blockIdx.z;
  const float* fT = fgdT + (size_t)b * sd;
  const float* gT = bgdT + (size_t)b * sd;
  __hip_bfloat16* Ao = AB + (size_t)b * sAB;
  __hip_bfloat16* Bo = Ao + (size_t)LQ * KSP;
  __shared__ float fs[96 * 65], gs[96 * 65];
  int q0 = blockIdx.x * 64;
  int tid = threadIdx.x;
#pragma unroll
  for (int i = 0; i < 24; ++i) {
    int e = i * 256 + tid;
    int c = e >> 6, qq = e & 63;
    fs[c * 65 + qq] = fT[c * LQ + q0 + qq];
    gs[c * 65 + qq] = gT[c * LQ + q0 + qq];
  }
  __syncthreads();
  for (int i = 0; i < 24; ++i) {
    int e = i * 256 + tid;               // 6144
    int qq = e / 96, k4 = (e % 96) * 4;
    unsigned short a4[4], b4[4];
    if (k4 < 288) {
      int part = k4 / 96, c = k4 % 96;
#pragma unroll
      for (int j = 0; j < 4; ++j) {
        float f = fs[(c + j) * 65 + qq];
        float g = gs[(c + j) * 65 + qq];
        __hip_bfloat16 fh = __float2bfloat16(f);
        __hip_bfloat16 gh = __float2bfloat16(g);
        __hip_bfloat16 fl = __float2bfloat16(f - __bfloat162float(fh));
        __hip_bfloat16 gl = __float2bfloat16(g - __bfloat162float(gh));
        __hip_bfloat16 av = (part == 2) ? fl : fh;              // {hi, hi, lo}
        __hip_bfloat16 bv = (part == 1) ? gl : gh;              // {hi, lo, hi}
        a4[j] = *(unsigned short*)&av;
        b4[j] = *(unsigned short*)&bv;
      }
    } else {
      a4[0] = a4[1] = a4[2] = a4[3] = 0;
      b4[0] = b4[1] = b4[2] = b4[3] = 0;
    }
    __builtin_memcpy(&Ao[(size_t)(q0 + qq) * KSP + k4], a4, 8);
    __builtin_memcpy(&Bo[(size_t)(q0 + qq) * KSP + k4], b4, 8);
  }
}

// ---------------- K1b: R[q][l] = sum_k A[q,k]*B[l,k]  (MFMA bf16 split, K=384)
__device__ __forceinline__ void gload16(const void* g, void* l) {
  __builtin_amdgcn_global_load_lds((const __attribute__((address_space(1))) void*)g,
                                   (__attribute__((address_space(3))) void*)l, 16, 0, 0);
}

__global__ __launch_bounds__(256) void k_rgemm_mfma(const __hip_bfloat16* __restrict__ AB,
                                                    float* __restrict__ R,
                                                    size_t sAB, size_t sR) {
  int bz = blockIdx.z;
  const __hip_bfloat16* Aq = AB + (size_t)bz * sAB;
  const __hip_bfloat16* Bq = Aq + (size_t)LQ * KSP;
  float* Rb = R + (size_t)bz * sR;
  __shared__ __align__(16) __hip_bfloat16 As[2][64 * 128];
  __shared__ __align__(16) __hip_bfloat16 Bs[2][64 * 128];
  int m0 = blockIdx.y * 64, n0 = blockIdx.x * 64;
  int tid = threadIdx.x;
  int w = tid >> 6, lane = tid & 63;
  int wm = w >> 1, wn = w & 1;
  f32x4 acc[2][2] = {};

  auto STAGE = [&](int buf, int k0) {
#pragma unroll
    for (int i = 0; i < 4; ++i) {
      int g = i * 256 + tid;
      int row = g >> 4, slot = g & 15;
      int ks = 8 * (slot ^ (row & 7));          // pre-swizzled source column
      gload16(Aq + (size_t)(m0 + row) * KSP + k0 + ks, &As[buf][g * 8]);
      gload16(Bq + (size_t)(n0 + row) * KSP + k0 + ks, &Bs[buf][g * 8]);
    }
  };

  STAGE(0, 0);
  __syncthreads();
  int cur = 0;
  for (int t = 0; t < 3; ++t) {
    if (t + 1 < 3) STAGE(cur ^ 1, (t + 1) * 128);
#pragma unroll
    for (int kk = 0; kk < 128; kk += 32) {
      bf16x8 af[2], bfr[2];
#pragma unroll
      for (int mi = 0; mi < 2; ++mi) {
        int row = wm * 32 + mi * 16 + (lane & 15);
        int e = (kk + (lane >> 4) * 8) ^ ((row & 7) * 8);   // read-side swizzle
        af[mi] = *(const bf16x8*)(&As[cur][row * 128 + e]);
      }
#pragma unroll
      for (int ni = 0; ni < 2; ++ni) {
        int row = wn * 32 + ni * 16 + (lane & 15);
        int e = (kk + (lane >> 4) * 8) ^ ((row & 7) * 8);
        bfr[ni] = *(const bf16x8*)(&Bs[cur][row * 128 + e]);
      }
#pragma unroll
      for (int mi = 0; mi < 2; ++mi)
#pragma unroll
        for (int ni = 0; ni < 2; ++ni)
          acc[mi][ni] = __builtin_amdgcn_mfma_f32_16x16x32_bf16(af[mi], bfr[ni], acc[mi][ni], 0, 0, 0);
    }
    __syncthreads();
    cur ^= 1;
  }

#pragma unroll
  for (int mi = 0; mi < 2; ++mi)
#pragma unroll
    for (int ni = 0; ni < 2; ++ni)
#pragma unroll
      for (int rr = 0; rr < 4; ++rr) {
        int row = m0 + wm * 32 + mi * 16 + (lane >> 4) * 4 + rr;
        int col = n0 + wn * 32 + ni * 16 + (lane & 15);
        Rb[(size_t)row * LQ + col] = acc[mi][ni][rr];
      }
}

// ---------------- K2: T9 in one pass (vectorized, XCD-striped, HOISTED loads):
// A2[q][l] = rn[l] * sum_{dy,dx} [2D-valid] R[q+48dy+dx][l+48dy+dx]
// All 9 taps loaded unconditionally (addresses stay inside d_ws; bufA sits
// ~449k floats into ws and max tap offset is +-113k floats), masks applied as
// selects AFTER the loads -> the 9 float4 loads issue together (ILP).
__global__ void k_t9v(const float* __restrict__ R, const float* __restrict__ rnorm,
                      float* __restrict__ A2, size_t sR, size_t sp) {
  int b = blockIdx.z;
  const float* S = R + (size_t)b * sR;
  const float* rn = rnorm + (size_t)b * sp;
  float* O = A2 + (size_t)b * sR;
  int bid = blockIdx.x;                        // 5184 = 8 * 648
  int wg = (bid & 7) * 648 + (bid >> 3);       // bijective XCD-stripe swizzle
  int t = wg * 256 + threadIdx.x;
  int id = t * 4;
  int q = id / LQ, l = id % LQ;
  int qy = q / ND, qx = q % ND;
  int ly = l / ND, lx0 = l % ND;               // lx0 in {0,4,...,44}; ly uniform over 4

  float4 L[3][3];
#pragma unroll
  for (int yy = 0; yy < 3; ++yy)
#pragma unroll
    for (int xx = 0; xx < 3; ++xx)
      L[yy][xx] = ld4u(S + id + ((yy - 1) * ND + (xx - 1)) * (LQ + 1));

  float4 r4 = *(const float4*)(rn + l);
  float4 acc = make_float4(0.f, 0.f, 0.f, 0.f);
#pragma unroll
  for (int yy = 0; yy < 3; ++yy) {
    int dy = yy - 1;
    bool oky = (qy + dy >= 0) && (qy + dy < ND) && (ly + dy >= 0) && (ly + dy < ND);
#pragma unroll
    for (int xx = 0; xx < 3; ++xx) {
      int dx = xx - 1;
      bool ok = oky && (qx + dx >= 0) && (qx + dx < ND);
      float4 m = L[yy][xx];
      if (dx == -1 && lx0 == 0) m.x = 0.f;          // lane lx==0 invalid for dx=-1
      if (dx == 1 && lx0 == ND - 4) m.w = 0.f;      // lane lx==47 invalid for dx=+1
      if (ok) {
        acc.x += m.x; acc.y += m.y; acc.z += m.z; acc.w += m.w;
      }
    }
  }
  acc.x *= r4.x; acc.y *= r4.y; acc.z *= r4.z; acc.w *= r4.w;
  *(float4*)(O + id) = acc;
}

// ---------------- K2c: flat diag fuse (vectorized, streaming, XCD-striped)
__global__ void k_fusev(const float* __restrict__ A2, float* __restrict__ F, size_t sR) {
  int b = blockIdx.z;
  const float* S = A2 + (size_t)b * sR;
  float* Fo = F + (size_t)b * sR;
  int bid = blockIdx.x;                        // 5184 = 8 * 648
  int wg = (bid & 7) * 648 + (bid >> 3);       // bijective XCD-stripe swizzle
  int t = wg * 256 + threadIdx.x;
  int id = t * 4;
  int a = id / LQ, bc0 = id % LQ;
  float4 c = *(const float4*)(S + id);
  float4 m = ld4u(S + id - LQ - 1);            // hoisted (safe inside ws)
  float4 p = ld4u(S + id + LQ + 1);
  if (a > 0) {
    if (bc0 == 0) m.x = 0.f;
    c.x += m.x; c.y += m.y; c.z += m.z; c.w += m.w;
  }
  if (a < LQ - 1) {
    if (bc0 == LQ - 4) p.w = 0.f;
    c.x += p.x; c.y += p.y; c.z += p.z; c.w += p.w;
  }
  *(float4*)(Fo + id) = c;
}

// ---------------- K3: second fuse (3 affine taps, quad-vectorized, HOISTED loads)
// + masked softmax. Wave-shfl reductions. XCD-striped (2304 = 8*288).
__global__ __launch_bounds__(256) void k_softmax(const float* __restrict__ F,
                                                 const float* __restrict__ mval,
                                                 __hip_bfloat16* __restrict__ P50s,
                                                 size_t sR, size_t sp, size_t sP) {
  int b = blockIdx.z;
  const float* Fb = F + (size_t)b * sR;
  const float* mv = mval + (size_t)b * sp;
  __hip_bfloat16* Pb = P50s + (size_t)b * sP + K2P;   // skip guard row
  int bid = blockIdx.x;
  int q = (bid & 7) * 288 + (bid >> 3);       // bijective XCD-stripe swizzle
  int qy = q / ND, qx = q % ND;
  int tid = threadIdx.x;
  __shared__ float wred[8];
  int fq0 = qx * ND + qy - 1, fq2 = qx * ND + qy + 1;
  bool qok0 = (fq0 >= 0), qok2 = (fq2 < LQ);
  const float* pm = Fb + (size_t)(qok0 ? (fq0 % ND) * ND + fq0 / ND : 0) * LQ;
  const float* pc = Fb + (size_t)q * LQ;     // gq1 == q exactly
  const float* pp = Fb + (size_t)(qok2 ? (fq2 % ND) * ND + fq2 / ND : 0) * LQ;

  // ---- load phase: all 12 float4 loads issued up front (ILP) ----
  float4 cv[3], t0v[3], t2v[3], m4v[3];
#pragma unroll
  for (int s = 0; s < 3; ++s) {
    int Qi = s * 256 + tid;
    int l = (Qi < 576) ? Qi * 4 : 0;          // clamp inactive to safe addr
    int ly = l / ND, lx0 = l % ND;
    cv[s]  = ld4u(pc + l);
    t0v[s] = (ly > 0) ? ld4u(pm + l - ND) : ld4u(pm + 2255 + lx0);
    t2v[s] = (ly < ND - 1) ? ld4u(pp + l + ND) : ld4u(pp + lx0 + 1);
    m4v[s] = ld4u(mv + l);
  }

  // ---- compute phase ----
  float lg[3][4], mq[3][4];
  float vmax = -1e30f;
#pragma unroll
  for (int s = 0; s < 3; ++s) {
    int Qi = s * 256 + tid;
    if (Qi < 576) {
      int l = Qi * 4;
      int ly = l / ND, lx0 = l % ND;
      float4 acc = cv[s];
      if (qok0) {
        float4 t0 = t0v[s];
        if (ly == 0 && lx0 == 0) t0.x = 0.f;  // corner (ly=0,lx=0)
        acc.x += t0.x; acc.y += t0.y; acc.z += t0.z; acc.w += t0.w;
      }
      if (qok2) {
        float4 t2 = t2v[s];
        if (ly == ND - 1 && lx0 == ND - 4) t2.w = 0.f;  // corner (ly=47,lx=47)
        acc.x += t2.x; acc.y += t2.y; acc.z += t2.z; acc.w += t2.w;
      }
      float4 m4 = m4v[s];
      mq[s][0] = m4.x; mq[s][1] = m4.y; mq[s][2] = m4.z; mq[s][3] = m4.w;
      lg[s][0] = acc.x * 10.0f * m4.x;
      lg[s][1] = acc.y * 10.0f * m4.y;
      lg[s][2] = acc.z * 10.0f * m4.z;
      lg[s][3] = acc.w * 10.0f * m4.w;
#pragma unroll
      for (int j = 0; j < 4; ++j) vmax = fmaxf(vmax, lg[s][j]);
    } else {
#pragma unroll
      for (int j = 0; j < 4; ++j) { lg[s][j] = -1e30f; mq[s][j] = 0.f; }
    }
  }
  // wave reduce max, then 4-wave combine
#pragma unroll
  for (int d = 32; d; d >>= 1) vmax = fmaxf(vmax, __shfl_xor(vmax, d));
  int wv = tid >> 6, lane = tid & 63;
  if (lane == 0) wred[wv] = vmax;
  __syncthreads();
  vmax = fmaxf(fmaxf(wred[0], wred[1]), fmaxf(wred[2], wred[3]));
  float ssum = 0.f;
#pragma unroll
  for (int s = 0; s < 3; ++s)
#pragma unroll
    for (int j = 0; j < 4; ++j) { lg[s][j] = __expf(lg[s][j] - vmax); ssum += lg[s][j]; }
#pragma unroll
  for (int d = 32; d; d >>= 1) ssum += __shfl_xor(ssum, d);
  if (lane == 0) wred[4 + wv] = ssum;
  __syncthreads();
  float inv = 1.0f / (wred[4] + wred[5] + wred[6] + wred[7]);
  // stores: col = l + 2*ly (50-grid); quad cols contiguous -> 2x u32 packed stores
#pragma unroll
  for (int s = 0; s < 3; ++s) {
    int Qi = s * 256 + tid;
    if (Qi >= 576) continue;
    int l = Qi * 4;
    int ly = l / ND;
    size_t base = (size_t)q * K2P + l + 2 * ly;   // even -> 4B-aligned byte addr
    unsigned int u01, u23;
    {
      __hip_bfloat16 h0 = __float2bfloat16(lg[s][0] * inv * mq[s][0]);
      __hip_bfloat16 h1 = __float2bfloat16(lg[s][1] * inv * mq[s][1]);
      unsigned short s0, s1;
      __builtin_memcpy(&s0, &h0, 2); __builtin_memcpy(&s1, &h1, 2);
      u01 = (unsigned int)s0 | ((unsigned int)s1 << 16);
      __hip_bfloat16 h2 = __float2bfloat16(lg[s][2] * inv * mq[s][2]);
      __hip_bfloat16 h3 = __float2bfloat16(lg[s][3] * inv * mq[s][3]);
      unsigned short s2, s3;
      __builtin_memcpy(&s2, &h2, 2); __builtin_memcpy(&s3, &h3, 2);
      u23 = (unsigned int)s2 | ((unsigned int)s3 << 16);
    }
    *(unsigned int*)((unsigned short*)Pb + base) = u01;
    *(unsigned int*)((unsigned short*)Pb + base + 2) = u23;
  }
  __hip_bfloat16 z = __float2bfloat16(0.f);
  // zero this row's 256 pad columns
  int pc2;
  if (tid < 96)        pc2 = (tid >> 1) * 50 + ND + (tid & 1);  // (m<48, n in {48,49})
  else if (tid < 196)  pc2 = 2400 + (tid - 96);                 // m in {48,49}
  else                 pc2 = 2500 + (tid - 196);                // tail
  Pb[(size_t)q * K2P + pc2] = z;
  // one block zeroes the guard row (absorbs q2v stencil underflow)
  if (q == 0)
    for (int i = tid; i < K2P; i += 256) (Pb - K2P)[i] = z;
}

// ---------------- K4a: Q2 = 4-flat-tap stencil of P50 (vectorized, XCD-striped)
__global__ void k_q2v(const __hip_bfloat16* __restrict__ P50s,
                      __hip_bfloat16* __restrict__ Q2, size_t sP, size_t sQ) {
  int bz = blockIdx.z;
  const __hip_bfloat16* P = P50s + (size_t)bz * sP + K2P;
  __hip_bfloat16* Q = Q2 + (size_t)bz * sQ;
  int bid = blockIdx.x;                        // 2880 = 8 * 360
  int wg = (bid & 7) * 360 + (bid >> 3);       // bijective XCD-stripe swizzle
  int id = wg * 256 + threadIdx.x;             // 2304*320 threads
  int r = id / 320, c8 = (id % 320) * 8;
  int a = r / ND, b = r % ND;
  const __hip_bfloat16* base = P + (size_t)r * K2P + c8;
  float acc[8];
  {  // tap (0,0) — aligned
    unsigned short s[8]; __builtin_memcpy(s, base, 16);
#pragma unroll
    for (int i = 0; i < 8; ++i) {
      unsigned int u = ((unsigned int)s[i]) << 16;
      acc[i] = __builtin_bit_cast(float, u);
    }
  }
  if (b >= 1) {   // tap (du=0,dv=1): offset -(K2P + 2)
    unsigned short s[8]; __builtin_memcpy(s, base - (K2P + 2), 16);
#pragma unroll
    for (int i = 0; i < 8; ++i) {
      unsigned int u = ((unsigned int)s[i]) << 16;
      acc[i] += __builtin_bit_cast(float, u);
    }
  }
  if (a >= 1) {   // tap (du=1,dv=0): offset -(48*K2P + 100)
    unsigned short s[8]; __builtin_memcpy(s, base - (ND * K2P + 100), 16);
#pragma unroll
    for (int i = 0; i < 8; ++i) {
      unsigned int u = ((unsigned int)s[i]) << 16;
      acc[i] += __builtin_bit_cast(float, u);
    }
  }
  if (a >= 1 && b >= 1) {   // tap (du=1,dv=1): offset -(49*K2P + 102)
    unsigned short s[8]; __builtin_memcpy(s, base - ((ND + 1) * K2P + 102), 16);
#pragma unroll
    for (int i = 0; i < 8; ++i) {
      unsigned int u = ((unsigned int)s[i]) << 16;
      acc[i] += __builtin_bit_cast(float, u);
    }
  }
  __hip_bfloat16 o[8];
#pragma unroll
  for (int i = 0; i < 8; ++i) o[i] = __float2bfloat16(acc[i]);
  *(bf16x8*)(Q + (size_t)r * K2P + c8) = *(bf16x8*)o;
}

// ---------------- K4b: B2[(c,s,t),(m,n)] = bgd[c, m+s-1, n+t-1] (zero-padded)
__global__ void k_b2(const float* __restrict__ bgdT, __hip_bfloat16* __restrict__ B2,
                     size_t sd, size_t sB) {
  int b = blockIdx.z;
  const float* gT = bgdT + (size_t)b * sd;
  __hip_bfloat16* Bb = B2 + (size_t)b * sB;
  int id = blockIdx.x * 256 + threadIdx.x;   // over 384*2560
  if (id >= NJ2 * K2P) return;
  int j = id / K2P, col = id % K2P;
  int c = j >> 2, s = (j >> 1) & 1, t = j & 1;
  float v = 0.f;
  if (col < 2500) {
    int m = col / 50, n = col % 50;
    int ry = m + s - 1, rx = n + t - 1;
    if (ry >= 0 && ry < ND && rx >= 0 && rx < ND)
      v = gT[c * LQ + ry * ND + rx];
  }
  Bb[id] = __float2bfloat16(v);
}

// ---------------- K5: bf16 MFMA GEMM: out = (1/16) * Q2 @ B2^T
__global__ __launch_bounds__(256) void k_gemm3(const __hip_bfloat16* __restrict__ A,
                                               const __hip_bfloat16* __restrict__ B,
                                               float* __restrict__ out,
                                               size_t sQ, size_t sB) {
  int bz = blockIdx.z;
  const __hip_bfloat16* Ab = A + (size_t)bz * sQ;
  const __hip_bfloat16* Bb = B + (size_t)bz * sB;
  float* ob = out + (size_t)bz * CHW;
  // XCD swizzle: grid.x = 216 = 8 XCDs * 27 contiguous tiles
  int wg = (blockIdx.x & 7) * 27 + (blockIdx.x >> 3);
  int n0 = (wg % 6) * 64, m0 = (wg / 6) * 64;
  __shared__ __align__(16) __hip_bfloat16 As[2][64 * 64];
  __shared__ __align__(16) __hip_bfloat16 Bs[2][64 * 64];
  int tid = threadIdx.x;
  int w = tid >> 6, lane = tid & 63;
  int wm = w >> 1, wn = w & 1;
  int l3 = lane >> 3, l7 = lane & 7;
  int kswz = (l7 * 8) ^ (l3 << 3);
  f32x4 acc[2][2] = {};

  auto STAGE = [&](int buf, int k0) {
#pragma unroll
    for (int i = 0; i < 2; ++i) {
      int chunk = w * 2 + i;                // 8 chunks x 8 rows = 64 rows
      int row = chunk * 8 + l3;
      gload16(Ab + (size_t)(m0 + row) * K2P + k0 + kswz, &As[buf][chunk * 8 * 64]);
      gload16(Bb + (size_t)(n0 + row) * K2P + k0 + kswz, &Bs[buf][chunk * 8 * 64]);
    }
  };

  STAGE(0, 0);
  __syncthreads();
  int cur = 0;
  constexpr int NT = K2P / 64;   // 40
  for (int t = 0; t < NT; ++t) {
    if (t + 1 < NT) STAGE(cur ^ 1, (t + 1) * 64);   // prefetch overlaps compute
#pragma unroll
    for (int kk = 0; kk < 64; kk += 32) {
      bf16x8 af[2], bfr[2];
#pragma unroll
      for (int mi = 0; mi < 2; ++mi) {
        int row = wm * 32 + mi * 16 + (lane & 15);
        int e = (kk + (lane >> 4) * 8) ^ ((row & 7) * 8);   // read-side swizzle
        af[mi] = *(const bf16x8*)(&As[cur][row * 64 + e]);
      }
#pragma unroll
      for (int ni = 0; ni < 2; ++ni) {
        int row = wn * 32 + ni * 16 + (lane & 15);
        int e = (kk + (lane >> 4) * 8) ^ ((row & 7) * 8);
        bfr[ni] = *(const bf16x8*)(&Bs[cur][row * 64 + e]);
      }
#pragma unroll
      for (int mi = 0; mi < 2; ++mi)
#pragma unroll
        for (int ni = 0; ni < 2; ++ni)
          acc[mi][ni] = __builtin_amdgcn_mfma_f32_16x16x32_bf16(af[mi], bfr[ni], acc[mi][ni], 0, 0, 0);
    }
    __syncthreads();
    cur ^= 1;
  }

#pragma unroll
  for (int mi = 0; mi < 2; ++mi)
#pragma unroll
    for (int ni = 0; ni < 2; ++ni)
#pragma unroll
      for (int rr = 0; rr < 4; ++rr) {
        int r_ = m0 + wm * 32 + mi * 16 + (lane >> 4) * 4 + rr;  // M row = a*48+b
        int j  = n0 + wn * 32 + ni * 16 + (lane & 15);           // N col = c*4+s*2+t
        int a = r_ / ND, bcol = r_ % ND;
        int c = j >> 2, s = (j >> 1) & 1, tt = j & 1;
        ob[((size_t)c * HWD + 2 * a + s) * HWD + 2 * bcol + tt] = acc[mi][ni][rr] * 0.0625f;
      }
}

extern "C" void kernel_launch(void* const* d_in, const int* in_sizes, int n_in,
                              void* d_out, int out_size, void* d_ws, size_t ws_size,
                              hipStream_t stream) {
  const float* fg_all = (const float*)d_in[0];
  const float* bg_all = (const float*)d_in[1];
  const float* mask_all = (const float*)d_in[2];
  float* out_all = (float*)d_out;
  float* ws = (float*)d_ws;

  int B = in_sizes[0] / CHW;

  const size_t S_D = (size_t)CCH * LQ;            // 221184 f32
  const size_t S_P = LQ;                          // 2304 f32
  const size_t S_R = (size_t)LQ * LQ;             // 5308416 f32
  const size_t S_P50 = (size_t)(LQ + 1) * K2P;    // 5900800 bf16 (incl guard row)
  const size_t per_floats = S_D * 2 + S_P * 3 + S_R * 2 + S_P50 / 2; // 14016512

  bool batched = ws_size >= (size_t)B * per_floats * 4;
  int na = batched ? B : 1;
  int nb = na;

  float* fgdT  = ws;
  float* bgdT  = fgdT + (size_t)na * S_D;
  float* n2    = bgdT + (size_t)na * S_D;
  float* rnorm = n2 + (size_t)na * S_P;
  float* mval  = rnorm + (size_t)na * S_P;
  float* bufA  = mval + (size_t)na * S_P;              // R, F, then Q2 (bf16 overlay)
  float* bufB  = bufA + (size_t)na * S_R;              // A2, then B2 (bf16 overlay)
  __hip_bfloat16* P50 = (__hip_bfloat16*)(bufB + (size_t)na * S_R);
  __hip_bfloat16* Q2  = (__hip_bfloat16*)bufA;         // 2304*2560 bf16 fits in S_R
  __hip_bfloat16* B2  = (__hip_bfloat16*)bufB;
  __hip_bfloat16* ABs = P50;   // split operands overlay the then-dead P50 region

  size_t sd = batched ? S_D : 0, sp = batched ? S_P : 0, sR = batched ? S_R : 0;
  size_t sP = batched ? S_P50 : 0;
  size_t sQ = batched ? S_R * 2 : 0;
  size_t sB = batched ? S_R * 2 : 0;

  for (int b0 = 0; b0 < B; b0 += nb) {
    const float* fg = fg_all + (size_t)(batched ? 0 : b0) * CHW;
    const float* bg = bg_all + (size_t)(batched ? 0 : b0) * CHW;
    const float* mask = mask_all + (size_t)(batched ? 0 : b0) * HW2;
    float* out = out_all + (size_t)(batched ? 0 : b0) * CHW;

    hipLaunchKernelGGL(k_downc, dim3(864, 1, nb), dim3(256), 0, stream,
                       fg, bg, fgdT, bgdT, sd);
    hipLaunchKernelGGL(k_n2, dim3(9, 1, nb), dim3(256), 0, stream,
                       bgdT, n2, sd, sp);
    hipLaunchKernelGGL(k_aux, dim3(9, 1, nb), dim3(256), 0, stream,
                       n2, mask, rnorm, mval, sp);
    hipLaunchKernelGGL(k_split, dim3(36, 1, nb), dim3(256), 0, stream,
                       fgdT, bgdT, ABs, sd, sP);
    hipLaunchKernelGGL(k_rgemm_mfma, dim3(36, 36, nb), dim3(256), 0, stream,
                       ABs, bufA, sP, sR);
    hipLaunchKernelGGL(k_t9v, dim3(5184, 1, nb), dim3(256), 0, stream,
                       bufA, rnorm, bufB, sR, sp);       // R -> A2
    hipLaunchKernelGGL(k_fusev, dim3(5184, 1, nb), dim3(256), 0, stream,
                       bufB, bufA, sR);                  // A2 -> F (R dead)
    hipLaunchKernelGGL(k_softmax, dim3(2304, 1, nb), dim3(256), 0, stream,
                       bufA, mval, P50, sR, sp, sP);     // F -> P50
    hipLaunchKernelGGL(k_q2v, dim3(2880, 1, nb), dim3(256), 0, stream,
                       P50, Q2, sP, sQ);                 // P50 -> Q2 (F dead)
    hipLaunchKernelGGL(k_b2, dim3(3840, 1, nb), dim3(256), 0, stream,
                       bgdT, B2, sd, sB);                // -> B2 (A2 dead)
    hipLaunchKernelGGL(k_gemm3, dim3(216, 1, nb), dim3(256), 0, stream,
                       Q2, B2, out, sQ, sB);
  }
}

// Round 18
// 236.861 us; speedup vs baseline: 1.0286x; 1.0286x over previous
//
#include <hip/hip_runtime.h>
#include <hip/hip_bf16.h>
#include <cstdint>
#include <cstring>

#define ND 48
#define LQ 2304      // 48*48
#define CCH 96
#define HWD 96
#define CHW (CCH*HWD*HWD)   // 884736
#define HW2 (HWD*HWD)       // 9216
#define K2P 2560     // padded K (50-grid: 2500 live, cols>=2500 zero)
#define NJ2 384      // 96 ch * 4 (s,t)
#define KSP 384      // split-GEMM K (288 live = 3 parts x 96, padded to 3x128)

typedef __attribute__((ext_vector_type(8))) short bf16x8;
typedef __attribute__((ext_vector_type(4))) float f32x4;

__device__ __forceinline__ float4 ld4u(const float* p) {  // 4B-aligned float4 load
  float4 v; __builtin_memcpy(&v, p, 16); return v;
}

// ---------------- K0a: downsample fg/bg to (c,p) layout (fully parallel copy)
__global__ void k_downc(const float* __restrict__ fg, const float* __restrict__ bg,
                        float* __restrict__ fgdT, float* __restrict__ bgdT, size_t sd) {
  int b = blockIdx.z;
  int id = blockIdx.x * 256 + threadIdx.x;   // < CCH*LQ = 221184 (864 blocks)
  int c = id / LQ, p = id % LQ;
  int py = p / ND, px = p % ND;
  size_t src = (size_t)b * CHW + (size_t)c * HW2 + (size_t)(2 * py) * HWD + 2 * px;
  fgdT[(size_t)b * sd + id] = fg[src];       // id == c*LQ + p (same layout)
  bgdT[(size_t)b * sd + id] = bg[src];
}

// ---------------- K0a': per-pos squared norm of bgd (reads L2-warm bgdT)
__global__ void k_n2(const float* __restrict__ bgdT, float* __restrict__ n2,
                     size_t sd, size_t sp) {
  int b = blockIdx.z;
  const float* bT = bgdT + (size_t)b * sd;
  int p = blockIdx.x * 256 + threadIdx.x;
  if (p >= LQ) return;
  float s = 0.f;
  for (int c = 0; c < CCH; ++c) {            // same c-ascending sum order as before
    float g = bT[c * LQ + p];
    s += g * g;
  }
  n2[(size_t)b * sp + p] = s;
}

// ---------------- K0b: patch norms (rnorm) and mask means (mval)
__global__ void k_aux(const float* __restrict__ n2, const float* __restrict__ mask,
                      float* __restrict__ rnorm, float* __restrict__ mval, size_t sp) {
  int b = blockIdx.z;
  const float* n2b = n2 + (size_t)b * sp;
  const float* mb = mask + (size_t)b * HW2;
  float* rn = rnorm + (size_t)b * sp;
  float* mv = mval + (size_t)b * sp;
  int p = blockIdx.x * 256 + threadIdx.x;
  if (p >= LQ) return;
  int py = p / ND, px = p % ND;
  float ssq = 0.f, ms = 0.f;
  for (int dy = -1; dy <= 1; ++dy)
    for (int dx = -1; dx <= 1; ++dx) {
      int yy = py + dy, xx = px + dx;
      if (yy >= 0 && yy < ND && xx >= 0 && xx < ND) {
        ssq += n2b[yy * ND + xx];
        ms  += mb[(2 * yy) * HWD + 2 * xx];
      }
    }
  rn[p] = 1.0f / sqrtf(ssq + 864.0f * 1e-9f);
  mv[p] = ms * (1.0f / 9.0f);
}

// ---------------- K1a: build split operands for MFMA rgemm
__global__ __launch_bounds__(256) void k_split(const float* __restrict__ fgdT,
                                               const float* __restrict__ bgdT,
                                               __hip_bfloat16* __restrict__ AB,
                                               size_t sd, size_t sAB) {
  int b = blockIdx.z;
  const float* fT = fgdT + (size_t)b * sd;
  const float* gT = bgdT + (size_t)b * sd;
  __hip_bfloat16* Ao = AB + (size_t)b * sAB;
  __hip_bfloat16* Bo = Ao + (size_t)LQ * KSP;
  __shared__ float fs[96 * 65], gs[96 * 65];
  int q0 = blockIdx.x * 64;
  int tid = threadIdx.x;
#pragma unroll
  for (int i = 0; i < 24; ++i) {
    int e = i * 256 + tid;
    int c = e >> 6, qq = e & 63;
    fs[c * 65 + qq] = fT[c * LQ + q0 + qq];
    gs[c * 65 + qq] = gT[c * LQ + q0 + qq];
  }
  __syncthreads();
  for (int i = 0; i < 24; ++i) {
    int e = i * 256 + tid;               // 6144
    int qq = e / 96, k4 = (e % 96) * 4;
    unsigned short a4[4], b4[4];
    if (k4 < 288) {
      int part = k4 / 96, c = k4 % 96;
#pragma unroll
      for (int j = 0; j < 4; ++j) {
        float f = fs[(c + j) * 65 + qq];
        float g = gs[(c + j) * 65 + qq];
        __hip_bfloat16 fh = __float2bfloat16(f);
        __hip_bfloat16 gh = __float2bfloat16(g);
        __hip_bfloat16 fl = __float2bfloat16(f - __bfloat162float(fh));
        __hip_bfloat16 gl = __float2bfloat16(g - __bfloat162float(gh));
        __hip_bfloat16 av = (part == 2) ? fl : fh;              // {hi, hi, lo}
        __hip_bfloat16 bv = (part == 1) ? gl : gh;              // {hi, lo, hi}
        a4[j] = *(unsigned short*)&av;
        b4[j] = *(unsigned short*)&bv;
      }
    } else {
      a4[0] = a4[1] = a4[2] = a4[3] = 0;
      b4[0] = b4[1] = b4[2] = b4[3] = 0;
    }
    __builtin_memcpy(&Ao[(size_t)(q0 + qq) * KSP + k4], a4, 8);
    __builtin_memcpy(&Bo[(size_t)(q0 + qq) * KSP + k4], b4, 8);
  }
}

// ---------------- K1b: R[q][l] = sum_k A[q,k]*B[l,k]  (MFMA bf16 split, K=384)
__device__ __forceinline__ void gload16(const void* g, void* l) {
  __builtin_amdgcn_global_load_lds((const __attribute__((address_space(1))) void*)g,
                                   (__attribute__((address_space(3))) void*)l, 16, 0, 0);
}

__global__ __launch_bounds__(256) void k_rgemm_mfma(const __hip_bfloat16* __restrict__ AB,
                                                    float* __restrict__ R,
                                                    size_t sAB, size_t sR) {
  int bz = blockIdx.z;
  const __hip_bfloat16* Aq = AB + (size_t)bz * sAB;
  const __hip_bfloat16* Bq = Aq + (size_t)LQ * KSP;
  float* Rb = R + (size_t)bz * sR;
  __shared__ __align__(16) __hip_bfloat16 As[2][64 * 128];
  __shared__ __align__(16) __hip_bfloat16 Bs[2][64 * 128];
  int m0 = blockIdx.y * 64, n0 = blockIdx.x * 64;
  int tid = threadIdx.x;
  int w = tid >> 6, lane = tid & 63;
  int wm = w >> 1, wn = w & 1;
  f32x4 acc[2][2] = {};

  auto STAGE = [&](int buf, int k0) {
#pragma unroll
    for (int i = 0; i < 4; ++i) {
      int g = i * 256 + tid;
      int row = g >> 4, slot = g & 15;
      int ks = 8 * (slot ^ (row & 7));          // pre-swizzled source column
      gload16(Aq + (size_t)(m0 + row) * KSP + k0 + ks, &As[buf][g * 8]);
      gload16(Bq + (size_t)(n0 + row) * KSP + k0 + ks, &Bs[buf][g * 8]);
    }
  };

  STAGE(0, 0);
  __syncthreads();
  int cur = 0;
  for (int t = 0; t < 3; ++t) {
    if (t + 1 < 3) STAGE(cur ^ 1, (t + 1) * 128);
#pragma unroll
    for (int kk = 0; kk < 128; kk += 32) {
      bf16x8 af[2], bfr[2];
#pragma unroll
      for (int mi = 0; mi < 2; ++mi) {
        int row = wm * 32 + mi * 16 + (lane & 15);
        int e = (kk + (lane >> 4) * 8) ^ ((row & 7) * 8);   // read-side swizzle
        af[mi] = *(const bf16x8*)(&As[cur][row * 128 + e]);
      }
#pragma unroll
      for (int ni = 0; ni < 2; ++ni) {
        int row = wn * 32 + ni * 16 + (lane & 15);
        int e = (kk + (lane >> 4) * 8) ^ ((row & 7) * 8);
        bfr[ni] = *(const bf16x8*)(&Bs[cur][row * 128 + e]);
      }
#pragma unroll
      for (int mi = 0; mi < 2; ++mi)
#pragma unroll
        for (int ni = 0; ni < 2; ++ni)
          acc[mi][ni] = __builtin_amdgcn_mfma_f32_16x16x32_bf16(af[mi], bfr[ni], acc[mi][ni], 0, 0, 0);
    }
    __syncthreads();
    cur ^= 1;
  }

#pragma unroll
  for (int mi = 0; mi < 2; ++mi)
#pragma unroll
    for (int ni = 0; ni < 2; ++ni)
#pragma unroll
      for (int rr = 0; rr < 4; ++rr) {
        int row = m0 + wm * 32 + mi * 16 + (lane >> 4) * 4 + rr;
        int col = n0 + wn * 32 + ni * 16 + (lane & 15);
        Rb[(size_t)row * LQ + col] = acc[mi][ni][rr];
      }
}

// ---------------- K2: T9 in one pass (vectorized, XCD-striped, hoisted loads)
__global__ void k_t9v(const float* __restrict__ R, const float* __restrict__ rnorm,
                      float* __restrict__ A2, size_t sR, size_t sp) {
  int b = blockIdx.z;
  const float* S = R + (size_t)b * sR;
  const float* rn = rnorm + (size_t)b * sp;
  float* O = A2 + (size_t)b * sR;
  int bid = blockIdx.x;                        // 5184 = 8 * 648
  int wg = (bid & 7) * 648 + (bid >> 3);       // bijective XCD-stripe swizzle
  int t = wg * 256 + threadIdx.x;
  int id = t * 4;
  int q = id / LQ, l = id % LQ;
  int qy = q / ND, qx = q % ND;
  int ly = l / ND, lx0 = l % ND;               // lx0 in {0,4,...,44}; ly uniform over 4

  float4 L[3][3];
#pragma unroll
  for (int yy = 0; yy < 3; ++yy)
#pragma unroll
    for (int xx = 0; xx < 3; ++xx)
      L[yy][xx] = ld4u(S + id + ((yy - 1) * ND + (xx - 1)) * (LQ + 1));

  float4 r4 = *(const float4*)(rn + l);
  float4 acc = make_float4(0.f, 0.f, 0.f, 0.f);
#pragma unroll
  for (int yy = 0; yy < 3; ++yy) {
    int dy = yy - 1;
    bool oky = (qy + dy >= 0) && (qy + dy < ND) && (ly + dy >= 0) && (ly + dy < ND);
#pragma unroll
    for (int xx = 0; xx < 3; ++xx) {
      int dx = xx - 1;
      bool ok = oky && (qx + dx >= 0) && (qx + dx < ND);
      float4 m = L[yy][xx];
      if (dx == -1 && lx0 == 0) m.x = 0.f;          // lane lx==0 invalid for dx=-1
      if (dx == 1 && lx0 == ND - 4) m.w = 0.f;      // lane lx==47 invalid for dx=+1
      if (ok) {
        acc.x += m.x; acc.y += m.y; acc.z += m.z; acc.w += m.w;
      }
    }
  }
  acc.x *= r4.x; acc.y *= r4.y; acc.z *= r4.z; acc.w *= r4.w;
  *(float4*)(O + id) = acc;
}

// ---------------- K2c: flat diag fuse (vectorized, streaming, XCD-striped)
__global__ void k_fusev(const float* __restrict__ A2, float* __restrict__ F, size_t sR) {
  int b = blockIdx.z;
  const float* S = A2 + (size_t)b * sR;
  float* Fo = F + (size_t)b * sR;
  int bid = blockIdx.x;                        // 5184 = 8 * 648
  int wg = (bid & 7) * 648 + (bid >> 3);       // bijective XCD-stripe swizzle
  int t = wg * 256 + threadIdx.x;
  int id = t * 4;
  int a = id / LQ, bc0 = id % LQ;
  float4 c = *(const float4*)(S + id);
  float4 m = ld4u(S + id - LQ - 1);            // hoisted (safe inside ws)
  float4 p = ld4u(S + id + LQ + 1);
  if (a > 0) {
    if (bc0 == 0) m.x = 0.f;
    c.x += m.x; c.y += m.y; c.z += m.z; c.w += m.w;
  }
  if (a < LQ - 1) {
    if (bc0 == LQ - 4) p.w = 0.f;
    c.x += p.x; c.y += p.y; c.z += p.z; c.w += p.w;
  }
  *(float4*)(Fo + id) = c;
}

// ---------------- K3: second fuse (3 affine taps, QUAD-VECTORIZED) + masked softmax.
// R16-verified form (conditional tap loads; VGPR 24, occupancy ~68%).
__global__ __launch_bounds__(256) void k_softmax(const float* __restrict__ F,
                                                 const float* __restrict__ mval,
                                                 __hip_bfloat16* __restrict__ P50s,
                                                 size_t sR, size_t sp, size_t sP) {
  int b = blockIdx.z;
  const float* Fb = F + (size_t)b * sR;
  const float* mv = mval + (size_t)b * sp;
  __hip_bfloat16* Pb = P50s + (size_t)b * sP + K2P;   // skip guard row
  int bid = blockIdx.x;
  int q = (bid & 7) * 288 + (bid >> 3);       // bijective XCD-stripe swizzle
  int qy = q / ND, qx = q % ND;
  int tid = threadIdx.x;
  __shared__ float wred[8];
  int fq0 = qx * ND + qy - 1, fq2 = qx * ND + qy + 1;
  bool qok0 = (fq0 >= 0), qok2 = (fq2 < LQ);
  const float* pm = Fb + (size_t)(qok0 ? (fq0 % ND) * ND + fq0 / ND : 0) * LQ;
  const float* pc = Fb + (size_t)q * LQ;     // gq1 == q exactly
  const float* pp = Fb + (size_t)(qok2 ? (fq2 % ND) * ND + fq2 / ND : 0) * LQ;

  float lg[3][4], mq[3][4];
  float vmax = -1e30f;
#pragma unroll
  for (int s = 0; s < 3; ++s) {
    int Qi = s * 256 + tid;
    bool act = (Qi < 576);
    if (act) {
      int l = Qi * 4;
      int ly = l / ND, lx0 = l % ND;          // quad-uniform ly; lx0 in {0,4,...,44}
      float4 acc = *(const float4*)(pc + l);  // center tap (aligned)
      if (qok0) {
        float4 t0 = (ly > 0) ? ld4u(pm + l - ND) : ld4u(pm + 2255 + lx0);
        if (ly == 0 && lx0 == 0) t0.x = 0.f;  // corner (ly=0,lx=0)
        acc.x += t0.x; acc.y += t0.y; acc.z += t0.z; acc.w += t0.w;
      }
      if (qok2) {
        float4 t2 = (ly < ND - 1) ? ld4u(pp + l + ND) : ld4u(pp + lx0 + 1);
        if (ly == ND - 1 && lx0 == ND - 4) t2.w = 0.f;  // corner (ly=47,lx=47)
        acc.x += t2.x; acc.y += t2.y; acc.z += t2.z; acc.w += t2.w;
      }
      float4 m4 = *(const float4*)(mv + l);
      mq[s][0] = m4.x; mq[s][1] = m4.y; mq[s][2] = m4.z; mq[s][3] = m4.w;
      lg[s][0] = acc.x * 10.0f * m4.x;
      lg[s][1] = acc.y * 10.0f * m4.y;
      lg[s][2] = acc.z * 10.0f * m4.z;
      lg[s][3] = acc.w * 10.0f * m4.w;
#pragma unroll
      for (int j = 0; j < 4; ++j) vmax = fmaxf(vmax, lg[s][j]);
    } else {
#pragma unroll
      for (int j = 0; j < 4; ++j) { lg[s][j] = -1e30f; mq[s][j] = 0.f; }
    }
  }
  // wave reduce max, then 4-wave combine
#pragma unroll
  for (int d = 32; d; d >>= 1) vmax = fmaxf(vmax, __shfl_xor(vmax, d));
  int wv = tid >> 6, lane = tid & 63;
  if (lane == 0) wred[wv] = vmax;
  __syncthreads();
  vmax = fmaxf(fmaxf(wred[0], wred[1]), fmaxf(wred[2], wred[3]));
  float ssum = 0.f;
#pragma unroll
  for (int s = 0; s < 3; ++s)
#pragma unroll
    for (int j = 0; j < 4; ++j) { lg[s][j] = __expf(lg[s][j] - vmax); ssum += lg[s][j]; }
#pragma unroll
  for (int d = 32; d; d >>= 1) ssum += __shfl_xor(ssum, d);
  if (lane == 0) wred[4 + wv] = ssum;
  __syncthreads();
  float inv = 1.0f / (wred[4] + wred[5] + wred[6] + wred[7]);
  // stores: col = l + 2*ly (50-grid); quad cols contiguous -> 2x u32 packed stores
#pragma unroll
  for (int s = 0; s < 3; ++s) {
    int Qi = s * 256 + tid;
    if (Qi >= 576) continue;
    int l = Qi * 4;
    int ly = l / ND;
    size_t base = (size_t)q * K2P + l + 2 * ly;   // even -> 4B-aligned byte addr
    unsigned int u01, u23;
    {
      __hip_bfloat16 h0 = __float2bfloat16(lg[s][0] * inv * mq[s][0]);
      __hip_bfloat16 h1 = __float2bfloat16(lg[s][1] * inv * mq[s][1]);
      unsigned short s0, s1;
      __builtin_memcpy(&s0, &h0, 2); __builtin_memcpy(&s1, &h1, 2);
      u01 = (unsigned int)s0 | ((unsigned int)s1 << 16);
      __hip_bfloat16 h2 = __float2bfloat16(lg[s][2] * inv * mq[s][2]);
      __hip_bfloat16 h3 = __float2bfloat16(lg[s][3] * inv * mq[s][3]);
      unsigned short s2, s3;
      __builtin_memcpy(&s2, &h2, 2); __builtin_memcpy(&s3, &h3, 2);
      u23 = (unsigned int)s2 | ((unsigned int)s3 << 16);
    }
    *(unsigned int*)((unsigned short*)Pb + base) = u01;
    *(unsigned int*)((unsigned short*)Pb + base + 2) = u23;
  }
  __hip_bfloat16 z = __float2bfloat16(0.f);
  // zero this row's 256 pad columns
  int pc2;
  if (tid < 96)        pc2 = (tid >> 1) * 50 + ND + (tid & 1);  // (m<48, n in {48,49})
  else if (tid < 196)  pc2 = 2400 + (tid - 96);                 // m in {48,49}
  else                 pc2 = 2500 + (tid - 196);                // tail
  Pb[(size_t)q * K2P + pc2] = z;
  // one block zeroes the guard row (absorbs q2v stencil underflow)
  if (q == 0)
    for (int i = tid; i < K2P; i += 256) (Pb - K2P)[i] = z;
}

// ---------------- K4a: Q2 = 4-flat-tap stencil of P50 (vectorized, XCD-striped)
__global__ void k_q2v(const __hip_bfloat16* __restrict__ P50s,
                      __hip_bfloat16* __restrict__ Q2, size_t sP, size_t sQ) {
  int bz = blockIdx.z;
  const __hip_bfloat16* P = P50s + (size_t)bz * sP + K2P;
  __hip_bfloat16* Q = Q2 + (size_t)bz * sQ;
  int bid = blockIdx.x;                        // 2880 = 8 * 360
  int wg = (bid & 7) * 360 + (bid >> 3);       // bijective XCD-stripe swizzle
  int id = wg * 256 + threadIdx.x;             // 2304*320 threads
  int r = id / 320, c8 = (id % 320) * 8;
  int a = r / ND, b = r % ND;
  const __hip_bfloat16* base = P + (size_t)r * K2P + c8;
  float acc[8];
  {  // tap (0,0) — aligned
    unsigned short s[8]; __builtin_memcpy(s, base, 16);
#pragma unroll
    for (int i = 0; i < 8; ++i) {
      unsigned int u = ((unsigned int)s[i]) << 16;
      acc[i] = __builtin_bit_cast(float, u);
    }
  }
  if (b >= 1) {   // tap (du=0,dv=1): offset -(K2P + 2)
    unsigned short s[8]; __builtin_memcpy(s, base - (K2P + 2), 16);
#pragma unroll
    for (int i = 0; i < 8; ++i) {
      unsigned int u = ((unsigned int)s[i]) << 16;
      acc[i] += __builtin_bit_cast(float, u);
    }
  }
  if (a >= 1) {   // tap (du=1,dv=0): offset -(48*K2P + 100)
    unsigned short s[8]; __builtin_memcpy(s, base - (ND * K2P + 100), 16);
#pragma unroll
    for (int i = 0; i < 8; ++i) {
      unsigned int u = ((unsigned int)s[i]) << 16;
      acc[i] += __builtin_bit_cast(float, u);
    }
  }
  if (a >= 1 && b >= 1) {   // tap (du=1,dv=1): offset -(49*K2P + 102)
    unsigned short s[8]; __builtin_memcpy(s, base - ((ND + 1) * K2P + 102), 16);
#pragma unroll
    for (int i = 0; i < 8; ++i) {
      unsigned int u = ((unsigned int)s[i]) << 16;
      acc[i] += __builtin_bit_cast(float, u);
    }
  }
  __hip_bfloat16 o[8];
#pragma unroll
  for (int i = 0; i < 8; ++i) o[i] = __float2bfloat16(acc[i]);
  *(bf16x8*)(Q + (size_t)r * K2P + c8) = *(bf16x8*)o;
}

// ---------------- K4b: B2[(c,s,t),(m,n)] = bgd[c, m+s-1, n+t-1] (zero-padded)
__global__ void k_b2(const float* __restrict__ bgdT, __hip_bfloat16* __restrict__ B2,
                     size_t sd, size_t sB) {
  int b = blockIdx.z;
  const float* gT = bgdT + (size_t)b * sd;
  __hip_bfloat16* Bb = B2 + (size_t)b * sB;
  int id = blockIdx.x * 256 + threadIdx.x;   // over 384*2560
  if (id >= NJ2 * K2P) return;
  int j = id / K2P, col = id % K2P;
  int c = j >> 2, s = (j >> 1) & 1, t = j & 1;
  float v = 0.f;
  if (col < 2500) {
    int m = col / 50, n = col % 50;
    int ry = m + s - 1, rx = n + t - 1;
    if (ry >= 0 && ry < ND && rx >= 0 && rx < ND)
      v = gT[c * LQ + ry * ND + rx];
  }
  Bb[id] = __float2bfloat16(v);
}

// ---------------- K5: bf16 MFMA GEMM: out = (1/16) * Q2 @ B2^T
__global__ __launch_bounds__(256) void k_gemm3(const __hip_bfloat16* __restrict__ A,
                                               const __hip_bfloat16* __restrict__ B,
                                               float* __restrict__ out,
                                               size_t sQ, size_t sB) {
  int bz = blockIdx.z;
  const __hip_bfloat16* Ab = A + (size_t)bz * sQ;
  const __hip_bfloat16* Bb = B + (size_t)bz * sB;
  float* ob = out + (size_t)bz * CHW;
  // XCD swizzle: grid.x = 216 = 8 XCDs * 27 contiguous tiles
  int wg = (blockIdx.x & 7) * 27 + (blockIdx.x >> 3);
  int n0 = (wg % 6) * 64, m0 = (wg / 6) * 64;
  __shared__ __align__(16) __hip_bfloat16 As[2][64 * 64];
  __shared__ __align__(16) __hip_bfloat16 Bs[2][64 * 64];
  int tid = threadIdx.x;
  int w = tid >> 6, lane = tid & 63;
  int wm = w >> 1, wn = w & 1;
  int l3 = lane >> 3, l7 = lane & 7;
  int kswz = (l7 * 8) ^ (l3 << 3);
  f32x4 acc[2][2] = {};

  auto STAGE = [&](int buf, int k0) {
#pragma unroll
    for (int i = 0; i < 2; ++i) {
      int chunk = w * 2 + i;                // 8 chunks x 8 rows = 64 rows
      int row = chunk * 8 + l3;
      gload16(Ab + (size_t)(m0 + row) * K2P + k0 + kswz, &As[buf][chunk * 8 * 64]);
      gload16(Bb + (size_t)(n0 + row) * K2P + k0 + kswz, &Bs[buf][chunk * 8 * 64]);
    }
  };

  STAGE(0, 0);
  __syncthreads();
  int cur = 0;
  constexpr int NT = K2P / 64;   // 40
  for (int t = 0; t < NT; ++t) {
    if (t + 1 < NT) STAGE(cur ^ 1, (t + 1) * 64);   // prefetch overlaps compute
#pragma unroll
    for (int kk = 0; kk < 64; kk += 32) {
      bf16x8 af[2], bfr[2];
#pragma unroll
      for (int mi = 0; mi < 2; ++mi) {
        int row = wm * 32 + mi * 16 + (lane & 15);
        int e = (kk + (lane >> 4) * 8) ^ ((row & 7) * 8);   // read-side swizzle
        af[mi] = *(const bf16x8*)(&As[cur][row * 64 + e]);
      }
#pragma unroll
      for (int ni = 0; ni < 2; ++ni) {
        int row = wn * 32 + ni * 16 + (lane & 15);
        int e = (kk + (lane >> 4) * 8) ^ ((row & 7) * 8);
        bfr[ni] = *(const bf16x8*)(&Bs[cur][row * 64 + e]);
      }
#pragma unroll
      for (int mi = 0; mi < 2; ++mi)
#pragma unroll
        for (int ni = 0; ni < 2; ++ni)
          acc[mi][ni] = __builtin_amdgcn_mfma_f32_16x16x32_bf16(af[mi], bfr[ni], acc[mi][ni], 0, 0, 0);
    }
    __syncthreads();
    cur ^= 1;
  }

#pragma unroll
  for (int mi = 0; mi < 2; ++mi)
#pragma unroll
    for (int ni = 0; ni < 2; ++ni)
#pragma unroll
      for (int rr = 0; rr < 4; ++rr) {
        int r_ = m0 + wm * 32 + mi * 16 + (lane >> 4) * 4 + rr;  // M row = a*48+b
        int j  = n0 + wn * 32 + ni * 16 + (lane & 15);           // N col = c*4+s*2+t
        int a = r_ / ND, bcol = r_ % ND;
        int c = j >> 2, s = (j >> 1) & 1, tt = j & 1;
        ob[((size_t)c * HWD + 2 * a + s) * HWD + 2 * bcol + tt] = acc[mi][ni][rr] * 0.0625f;
      }
}

extern "C" void kernel_launch(void* const* d_in, const int* in_sizes, int n_in,
                              void* d_out, int out_size, void* d_ws, size_t ws_size,
                              hipStream_t stream) {
  const float* fg_all = (const float*)d_in[0];
  const float* bg_all = (const float*)d_in[1];
  const float* mask_all = (const float*)d_in[2];
  float* out_all = (float*)d_out;
  float* ws = (float*)d_ws;

  int B = in_sizes[0] / CHW;

  const size_t S_D = (size_t)CCH * LQ;            // 221184 f32
  const size_t S_P = LQ;                          // 2304 f32
  const size_t S_R = (size_t)LQ * LQ;             // 5308416 f32
  const size_t S_P50 = (size_t)(LQ + 1) * K2P;    // 5900800 bf16 (incl guard row)
  const size_t per_floats = S_D * 2 + S_P * 3 + S_R * 2 + S_P50 / 2; // 14016512

  bool batched = ws_size >= (size_t)B * per_floats * 4;
  int na = batched ? B : 1;
  int nb = na;

  float* fgdT  = ws;
  float* bgdT  = fgdT + (size_t)na * S_D;
  float* n2    = bgdT + (size_t)na * S_D;
  float* rnorm = n2 + (size_t)na * S_P;
  float* mval  = rnorm + (size_t)na * S_P;
  float* bufA  = mval + (size_t)na * S_P;              // R, F, then Q2 (bf16 overlay)
  float* bufB  = bufA + (size_t)na * S_R;              // A2, then B2 (bf16 overlay)
  __hip_bfloat16* P50 = (__hip_bfloat16*)(bufB + (size_t)na * S_R);
  __hip_bfloat16* Q2  = (__hip_bfloat16*)bufA;         // 2304*2560 bf16 fits in S_R
  __hip_bfloat16* B2  = (__hip_bfloat16*)bufB;
  __hip_bfloat16* ABs = P50;   // split operands overlay the then-dead P50 region

  size_t sd = batched ? S_D : 0, sp = batched ? S_P : 0, sR = batched ? S_R : 0;
  size_t sP = batched ? S_P50 : 0;
  size_t sQ = batched ? S_R * 2 : 0;
  size_t sB = batched ? S_R * 2 : 0;

  for (int b0 = 0; b0 < B; b0 += nb) {
    const float* fg = fg_all + (size_t)(batched ? 0 : b0) * CHW;
    const float* bg = bg_all + (size_t)(batched ? 0 : b0) * CHW;
    const float* mask = mask_all + (size_t)(batched ? 0 : b0) * HW2;
    float* out = out_all + (size_t)(batched ? 0 : b0) * CHW;

    hipLaunchKernelGGL(k_downc, dim3(864, 1, nb), dim3(256), 0, stream,
                       fg, bg, fgdT, bgdT, sd);
    hipLaunchKernelGGL(k_n2, dim3(9, 1, nb), dim3(256), 0, stream,
                       bgdT, n2, sd, sp);
    hipLaunchKernelGGL(k_aux, dim3(9, 1, nb), dim3(256), 0, stream,
                       n2, mask, rnorm, mval, sp);
    hipLaunchKernelGGL(k_split, dim3(36, 1, nb), dim3(256), 0, stream,
                       fgdT, bgdT, ABs, sd, sP);
    hipLaunchKernelGGL(k_rgemm_mfma, dim3(36, 36, nb), dim3(256), 0, stream,
                       ABs, bufA, sP, sR);
    hipLaunchKernelGGL(k_t9v, dim3(5184, 1, nb), dim3(256), 0, stream,
                       bufA, rnorm, bufB, sR, sp);       // R -> A2
    hipLaunchKernelGGL(k_fusev, dim3(5184, 1, nb), dim3(256), 0, stream,
                       bufB, bufA, sR);                  // A2 -> F (R dead)
    hipLaunchKernelGGL(k_softmax, dim3(2304, 1, nb), dim3(256), 0, stream,
                       bufA, mval, P50, sR, sp, sP);     // F -> P50
    hipLaunchKernelGGL(k_q2v, dim3(2880, 1, nb), dim3(256), 0, stream,
                       P50, Q2, sP, sQ);                 // P50 -> Q2 (F dead)
    hipLaunchKernelGGL(k_b2, dim3(3840, 1, nb), dim3(256), 0, stream,
                       bgdT, B2, sd, sB);                // -> B2 (A2 dead)
    hipLaunchKernelGGL(k_gemm3, dim3(216, 1, nb), dim3(256), 0, stream,
                       Q2, B2, out, sQ, sB);
  }
}